// Round 2
// baseline (258.754 us; speedup 1.0000x reference)
//
#include <hip/hip_runtime.h>
#include <hip/hip_bf16.h>
#include <cstdint>
#include <cstddef>

typedef __bf16 bf16;
typedef __bf16 bf16x2 __attribute__((ext_vector_type(2)));
typedef __bf16 bf16x4 __attribute__((ext_vector_type(4)));
typedef __bf16 bf16x8 __attribute__((ext_vector_type(8)));
typedef float  f32x4  __attribute__((ext_vector_type(4)));

// async global->LDS, 16B per lane. LDS dest = wave-uniform base + lane*16B.
__device__ __forceinline__ void async_copy16(const void* g, void* l) {
  __builtin_amdgcn_global_load_lds((const __attribute__((address_space(1))) void*)g,
                                   (__attribute__((address_space(3))) void*)l,
                                   16, 0, 0);
}

// LDS 64B-row swizzle: elem ^= ((row>>1)&3)<<3 (byte<<4). Involution confined
// to the 32-elem row; spreads 16-lane ds_read_b128 windows across all eight
// 16B bank-groups. Applied as inverse on the global SOURCE of global_load_lds
// (LDS dest stays linear, per rule #21) and on the ds_read address.
__device__ __forceinline__ int swz(int row) { return ((row >> 1) & 3) << 3; }

// Per-block dtype flag from hs[0..127] words: fp32 mantissa-garbage decoded as
// bf16 has exponent >= 134 ~50% of the time; real bf16 N(0,1) never does.
__device__ __forceinline__ bool block_flag_is_f32(const unsigned int* w, int tid,
                                                  int* sflag) {
  if (tid < 64) {
    int weird = 0;
#pragma unroll
    for (int c = 0; c < 2; ++c) {
      const unsigned int lo = w[c * 64 + tid] & 0xffffu;
      const unsigned int ex = (lo >> 7) & 0xffu;
      if (ex >= 134u) ++weird;
    }
    const unsigned long long m1 = __ballot(weird >= 1);
    const unsigned long long m2 = __ballot(weird == 2);
    if (tid == 0) *sflag = (__popcll(m1) + __popcll(m2) >= 8) ? 1 : 0;
  }
  __syncthreads();
  return *sflag != 0;
}

// ---------------------------------------------------------------------------
// Fused convert (float4-unit indexed), flag computed per-block, block 0 also
// zero-inits ssum[2048].
// ---------------------------------------------------------------------------
__global__ __launch_bounds__(256) void convert_all(
    const void* __restrict__ s0, const void* __restrict__ s1,
    const void* __restrict__ s2, const void* __restrict__ s3,
    bf16* __restrict__ d0, bf16* __restrict__ d1, bf16* __restrict__ d2,
    float* __restrict__ ssum) {
  __shared__ int sflag;
  const int tid = threadIdx.x;
  const bool f32 = block_flag_is_f32((const unsigned int*)s0, tid, &sflag);
  if (blockIdx.x == 0) {
    ((float4*)ssum)[tid * 2]     = make_float4(0.f, 0.f, 0.f, 0.f);
    ((float4*)ssum)[tid * 2 + 1] = make_float4(0.f, 0.f, 0.f, 0.f);
  }
  const int i = blockIdx.x * 256 + tid;
  if (i >= 3670016) return;
  const void* src; bf16* dst; int off; bool fold = false;
  if      (i < 1048576) { src = s0; dst = d0; off = i; }
  else if (i < 2621440) { src = s1; dst = d1; off = i - 1048576; }
  else                  { src = s2; dst = d2; off = i - 2621440; fold = true; }
  float v[4];
  if (f32) {
    const float4 t = ((const float4*)src)[off];
    v[0] = t.x; v[1] = t.y; v[2] = t.z; v[3] = t.w;
  } else {
    const bf16x4 t = ((const bf16x4*)src)[off];
#pragma unroll
    for (int j = 0; j < 4; ++j) v[j] = (float)t[j];
  }
  if (fold) {
    const int k0 = (off * 4) & 2047;
#pragma unroll
    for (int j = 0; j < 4; ++j) {
      const float w = f32 ? ((const float*)s3)[k0 + j] : (float)((const bf16*)s3)[k0 + j];
      v[j] *= w;
    }
  }
  bf16x4 o;
#pragma unroll
  for (int j = 0; j < 4; ++j) o[j] = (bf16)v[j];
  *(bf16x4*)(dst + (size_t)off * 4) = o;
}

// ---------------------------------------------------------------------------
// GEMM1 + fused neox RoPE epilogue. m97-class structure: 128x128 tile,
// 4 waves (2x2) each owning 64x64 (4x4 acc), BK=32 double-buffered (32KB LDS,
// ~4 blocks/CU), 2-phase stage(next)->compute(cur)->barrier. Swizzled
// source + swizzled ds_read (T2).
// Q is scaled by SCALE*log2e so attention softmax runs in exp2 space.
// V is written with seq permuted within 32-blocks: s' = (s&~31) + κ⁻¹(s&31),
// κ⁻¹(k) = (k&15)*2 + (k>>4), matching attention's packed-P key order.
// ---------------------------------------------------------------------------
__global__ __launch_bounds__(256) void gemm_qkv_rope(
    const bf16* __restrict__ A, const bf16* __restrict__ B,
    const int* __restrict__ pos,
    bf16* __restrict__ Q, bf16* __restrict__ K, bf16* __restrict__ V)
{
  __shared__ __align__(16) bf16 As[2][128 * 32];   // 2 x 8KB [row][32]
  __shared__ __align__(16) bf16 Bs[2][128 * 32];   // 2 x 8KB
  const int tid = threadIdx.x, wave = tid >> 6, lane = tid & 63;
  const int l15 = lane & 15, l4 = lane >> 4;
  const int m0 = blockIdx.y * 128, n0 = blockIdx.x * 128;
  const int wm = (wave >> 1) * 64, wn = (wave & 1) * 64;
  const int swz_ro = (l4 * 8) ^ swz(l15);

  f32x4 acc[4][4] = {};

  auto stage = [&](int buf, int kt) {
#pragma unroll
    for (int c = 0; c < 2; ++c) {
      const int e = c * 2048 + tid * 8;
      const int row = e >> 5;
      const int o = (e & 31) ^ swz(row);           // inverse-swizzled source
      async_copy16(A + (size_t)(m0 + row) * 2048 + kt + o, &As[buf][e]);
      async_copy16(B + (size_t)(n0 + row) * 2048 + kt + o, &Bs[buf][e]);
    }
  };

  stage(0, 0);
  __syncthreads();
  int cur = 0;
  for (int kt = 0; kt < 2048; kt += 32) {
    if (kt + 32 < 2048) stage(cur ^ 1, kt + 32);   // prefetch overlaps compute
    bf16x8 af[4], bfr[4];
#pragma unroll
    for (int i = 0; i < 4; ++i)
      af[i] = *(const bf16x8*)(&As[cur][(wm + i * 16 + l15) * 32 + swz_ro]);
#pragma unroll
    for (int j = 0; j < 4; ++j)
      bfr[j] = *(const bf16x8*)(&Bs[cur][(wn + j * 16 + l15) * 32 + swz_ro]);
#pragma unroll
    for (int i = 0; i < 4; ++i)
#pragma unroll
      for (int j = 0; j < 4; ++j)
        acc[i][j] = __builtin_amdgcn_mfma_f32_16x16x32_bf16(af[i], bfr[j], acc[i][j], 0, 0, 0);
    __syncthreads();
    cur ^= 1;
  }

  if (n0 < 2560) {  // Q or K: rope in-register
    const bool isQ = (n0 < 2048);
#pragma unroll
    for (int i = 0; i < 4; ++i)
#pragma unroll
      for (int j = 0; j < 4; ++j) {
        const int col = n0 + wn + j * 16 + l15;
        const int hd = isQ ? col : (col - 2048);
        const int hh = hd >> 6, d = hd & 63;
        const int fi = d & 31;
        const float ifr = __expf((float)fi * -0.41007385554f);  // theta^(-fi/32)
#pragma unroll
        for (int r = 0; r < 4; ++r) {
          const int m = m0 + wm + i * 16 + l4 * 4 + r;
          const int b = m >> 10, s = m & 1023;
          const float ang = (float)pos[m] * ifr;
          float sn, cs;
          __sincosf(ang, &sn, &cs);
          const float x  = acc[i][j][r];
          const float xp = acc[i][j ^ 2][r];   // partner (col^32)
          const float v = (d < 32) ? (x * cs - xp * sn) : (x * cs + xp * sn);
          // Q folded scale = 0.125 * log2(e) -> softmax in exp2 space
          if (isQ) Q[(((size_t)(b * 32 + hh)) * 1024 + s) * 64 + d] = (bf16)(v * 0.1803368801f);
          else     K[(((size_t)(b * 8 + hh)) * 1024 + s) * 64 + d] = (bf16)v;
        }
      }
  } else {          // V: transpose to [B,NKV,64,S], seq permuted within 32
#pragma unroll
    for (int i = 0; i < 4; ++i)
#pragma unroll
      for (int j = 0; j < 4; ++j) {
        const int cv = n0 + wn + j * 16 + l15 - 2560;
        const int hh = cv >> 6, d = cv & 63;
#pragma unroll
        for (int r = 0; r < 4; ++r) {
          const int m = m0 + wm + i * 16 + l4 * 4 + r;
          const int b = m >> 10, s = m & 1023;
          const int sp = (s & ~31) + ((s & 15) * 2 + ((s >> 4) & 1));
          V[(((size_t)(b * 8 + hh)) * 64 + d) * 1024 + sp] = (bf16)acc[i][j][r];
        }
      }
  }
}

// ---------------------------------------------------------------------------
// Flash attention. Round-0 structure restored (single-buffer Ks/Vs staged via
// global_load_lds, 2 barriers/tile, no reg-prefetch) — with the bank-conflict
// fix done the occupancy-free way: inverse-swizzled global SOURCE addresses
// (LDS dest linear) + swizzled ds_read. exp2-space numerics (log2e folded
// into Q). Defer-max (T13, THR=8 log2-units): wave-uniform fast path skips
// the alpha-rescale of o_acc/l when the running max didn't grow (exact).
// P written as packed b32 in κ-permuted key order; V global layout permuted
// to match (dot product invariant).
// ---------------------------------------------------------------------------
__global__ __launch_bounds__(256) void attn_kernel(
    const bf16* __restrict__ Q, const bf16* __restrict__ K,
    const bf16* __restrict__ Vt, bf16* __restrict__ O, float* __restrict__ ssum)
{
  __shared__ __align__(16) bf16 Ks[2 * 128 * 32];   // 16KB [dchunk][key][32]
  __shared__ __align__(16) bf16 Vs[4 * 64 * 32];    // 16KB [kchunk][d][32]
  __shared__ __align__(16) bf16 Ps[4 * 128 * 40];   // 40KB [kchunk][q][40]; Q-stage reuse

  const int tid = threadIdx.x, wave = tid >> 6, lane = tid & 63;
  const int l15 = lane & 15, l4 = lane >> 4;
  const int swz_ro = (l4 * 8) ^ swz(l15);
  const int ip = blockIdx.x, bh = blockIdx.y;
  const int b = bh >> 5, h = bh & 31, kvh = h >> 2;
  const int qlo = ip * 64, qhi = (15 - ip) * 64;
  const bf16* Qb = Q + ((size_t)(b * 32 + h)) * 65536;
  const bf16* Kb = K + ((size_t)(b * 8 + kvh)) * 65536;
  const bf16* Vb = Vt + ((size_t)(b * 8 + kvh)) * 65536;

#pragma unroll
  for (int c = 0; c < 4; ++c) {
    const int e = c * 2048 + tid * 8;
    const int dchunk = e >> 12;
    const int row = (e & 4095) >> 5;
    const int qb = (row < 64) ? qlo : qhi;
    const int o = (e & 31) ^ swz(row);
    async_copy16(Qb + (size_t)(qb + (row & 63)) * 64 + dchunk * 32 + o, Ps + e);
  }
  __syncthreads();
  bf16x8 aq[2][2];   // [half][dchunk]
#pragma unroll
  for (int i = 0; i < 2; ++i)
#pragma unroll
    for (int s = 0; s < 2; ++s)
      aq[i][s] = *(const bf16x8*)(Ps + s * 4096 + (i * 64 + wave * 16 + l15) * 32 + swz_ro);
  __syncthreads();

  float m_s[2][4], l_s[2][4];
  f32x4 o_acc[2][4] = {};
#pragma unroll
  for (int i = 0; i < 2; ++i)
#pragma unroll
    for (int r = 0; r < 4; ++r) { m_s[i][r] = -3.0e4f; l_s[i][r] = 0.f; }

  const int nkt = (1151 - 64 * ip) >> 7;
  for (int kt = 0; kt < nkt; ++kt) {
    const int k0 = kt * 128;
    const bool lo_act = (k0 < (ip + 1) * 64);
#pragma unroll
    for (int c = 0; c < 4; ++c) {
      const int e = c * 2048 + tid * 8;
      const int krow = (e & 4095) >> 5;
      const int ko = (e & 31) ^ swz(krow);
      async_copy16(Kb + (size_t)(k0 + krow) * 64 + (e >> 12) * 32 + ko, Ks + e);
      const int drow = (e & 2047) >> 5;
      const int vo = (e & 31) ^ swz(drow);
      async_copy16(Vb + (size_t)drow * 1024 + k0 + (e >> 11) * 32 + vo, Vs + e);
    }
    __syncthreads();

    f32x4 sc[2][8] = {};
#pragma unroll
    for (int j = 0; j < 8; ++j) {
      const bf16x8 bk0 = *(const bf16x8*)(Ks + (j * 16 + l15) * 32 + swz_ro);
      const bf16x8 bk1 = *(const bf16x8*)(Ks + 4096 + (j * 16 + l15) * 32 + swz_ro);
      sc[1][j] = __builtin_amdgcn_mfma_f32_16x16x32_bf16(aq[1][0], bk0, sc[1][j], 0, 0, 0);
      sc[1][j] = __builtin_amdgcn_mfma_f32_16x16x32_bf16(aq[1][1], bk1, sc[1][j], 0, 0, 0);
      if (lo_act) {
        sc[0][j] = __builtin_amdgcn_mfma_f32_16x16x32_bf16(aq[0][0], bk0, sc[0][j], 0, 0, 0);
        sc[0][j] = __builtin_amdgcn_mfma_f32_16x16x32_bf16(aq[0][1], bk1, sc[0][j], 0, 0, 0);
      }
    }

#pragma unroll
    for (int hh = 0; hh < 2; ++hh) {
      if (hh == 0 && !lo_act) continue;
      const int qb = hh ? qhi : qlo;
      float mxv[4];
      bool grow = false;
#pragma unroll
      for (int r = 0; r < 4; ++r) {
        const int rg = qb + wave * 16 + l4 * 4 + r;
        float mx = -3.0e4f;
#pragma unroll
        for (int j = 0; j < 8; ++j) {
          float v = sc[hh][j][r];
          if (k0 + j * 16 + l15 > rg) v = -3.0e4f;
          sc[hh][j][r] = v;
          mx = fmaxf(mx, v);
        }
#pragma unroll
        for (int off = 1; off < 16; off <<= 1) mx = fmaxf(mx, __shfl_xor(mx, off));
        mxv[r] = mx;
        grow = grow || (mx > m_s[hh][r] + 8.0f);
      }
      if (__all(!grow)) {
        // fast path: running max kept, no rescale (exact; P bounded by 2^8)
#pragma unroll
        for (int r = 0; r < 4; ++r) {
          const int rl = wave * 16 + l4 * 4 + r;
          const float m = m_s[hh][r];
          float rs = 0.f;
#pragma unroll
          for (int t = 0; t < 4; ++t) {
            const float pv0 = exp2f(sc[hh][2 * t][r]     - m);
            const float pv1 = exp2f(sc[hh][2 * t + 1][r] - m);
            rs += pv0 + pv1;
            bf16x2 pk; pk[0] = (bf16)pv0; pk[1] = (bf16)pv1;
            *(bf16x2*)(Ps + t * 5120 + (hh * 64 + rl) * 40 + l15 * 2) = pk;
          }
#pragma unroll
          for (int off = 1; off < 16; off <<= 1) rs += __shfl_xor(rs, off);
          l_s[hh][r] += rs;
        }
      } else {
#pragma unroll
        for (int r = 0; r < 4; ++r) {
          const int rl = wave * 16 + l4 * 4 + r;
          const float mnew = fmaxf(m_s[hh][r], mxv[r]);
          const float alpha = exp2f(m_s[hh][r] - mnew);
          m_s[hh][r] = mnew;
          float rs = 0.f;
#pragma unroll
          for (int t = 0; t < 4; ++t) {
            const float pv0 = exp2f(sc[hh][2 * t][r]     - mnew);
            const float pv1 = exp2f(sc[hh][2 * t + 1][r] - mnew);
            rs += pv0 + pv1;
            bf16x2 pk; pk[0] = (bf16)pv0; pk[1] = (bf16)pv1;
            *(bf16x2*)(Ps + t * 5120 + (hh * 64 + rl) * 40 + l15 * 2) = pk;
          }
#pragma unroll
          for (int off = 1; off < 16; off <<= 1) rs += __shfl_xor(rs, off);
          l_s[hh][r] = l_s[hh][r] * alpha + rs;
#pragma unroll
          for (int jd = 0; jd < 4; ++jd) o_acc[hh][jd][r] *= alpha;
        }
      }
    }
    // NOTE: no __syncthreads here — P rows are written and read by the same
    // wave (A-frag row = hh*64 + wave*16 + l15); LDS ops are wave-ordered.

#pragma unroll
    for (int ks = 0; ks < 4; ++ks) {
      bf16x8 bv[4];
#pragma unroll
      for (int jd = 0; jd < 4; ++jd)
        bv[jd] = *(const bf16x8*)(Vs + ks * 2048 + (jd * 16 + l15) * 32 + swz_ro);
#pragma unroll
      for (int hh = 0; hh < 2; ++hh) {
        if (hh == 0 && !lo_act) continue;
        const bf16x8 ap = *(const bf16x8*)(Ps + ks * 5120 + (hh * 64 + wave * 16 + l15) * 40 + l4 * 8);
#pragma unroll
        for (int jd = 0; jd < 4; ++jd)
          o_acc[hh][jd] = __builtin_amdgcn_mfma_f32_16x16x32_bf16(ap, bv[jd], o_acc[hh][jd], 0, 0, 0);
      }
    }
    __syncthreads();
  }

  // ---- epilogue: O /= l, write [B*S, NH*64]; accumulate row sum-of-squares
#pragma unroll
  for (int hh = 0; hh < 2; ++hh) {
    const int qb = hh ? qhi : qlo;
#pragma unroll
    for (int r = 0; r < 4; ++r) {
      const float inv = 1.0f / l_s[hh][r];
      const int srow = qb + wave * 16 + l4 * 4 + r;
      bf16* op = O + ((size_t)(b * 1024 + srow)) * 2048 + h * 64;
      float ss = 0.f;
#pragma unroll
      for (int jd = 0; jd < 4; ++jd) {
        const float v = o_acc[hh][jd][r] * inv;
        op[jd * 16 + l15] = (bf16)v;
        ss += v * v;
      }
#pragma unroll
      for (int off = 1; off < 16; off <<= 1) ss += __shfl_xor(ss, off);
      if (l15 == 0) atomicAdd(&ssum[b * 1024 + srow], ss);
    }
  }
}

// ---------------------------------------------------------------------------
// GEMM2: out = rsqrt(mean(ssum)+eps)[m] * (attn_o x w_o'^T). Same m97-class
// 128x128 / BK=32 double-buffered structure as gemm_qkv_rope.
// ---------------------------------------------------------------------------
__global__ __launch_bounds__(256) void gemm_out(
    const bf16* __restrict__ A, const bf16* __restrict__ B,
    const float* __restrict__ ssum, const unsigned int* __restrict__ hs_raw,
    void* __restrict__ out)
{
  __shared__ __align__(16) bf16 As[2][128 * 32];
  __shared__ __align__(16) bf16 Bs[2][128 * 32];
  __shared__ int sflag;
  const int tid = threadIdx.x, wave = tid >> 6, lane = tid & 63;
  const bool f32out = block_flag_is_f32(hs_raw, tid, &sflag);
  const int l15 = lane & 15, l4 = lane >> 4;
  const int m0 = blockIdx.y * 128, n0 = blockIdx.x * 128;
  const int wm = (wave >> 1) * 64, wn = (wave & 1) * 64;
  const int swz_ro = (l4 * 8) ^ swz(l15);

  f32x4 acc[4][4] = {};

  auto stage = [&](int buf, int kt) {
#pragma unroll
    for (int c = 0; c < 2; ++c) {
      const int e = c * 2048 + tid * 8;
      const int row = e >> 5;
      const int o = (e & 31) ^ swz(row);
      async_copy16(A + (size_t)(m0 + row) * 2048 + kt + o, &As[buf][e]);
      async_copy16(B + (size_t)(n0 + row) * 2048 + kt + o, &Bs[buf][e]);
    }
  };

  stage(0, 0);
  __syncthreads();
  int cur = 0;
  for (int kt = 0; kt < 2048; kt += 32) {
    if (kt + 32 < 2048) stage(cur ^ 1, kt + 32);
    bf16x8 af[4], bfr[4];
#pragma unroll
    for (int i = 0; i < 4; ++i)
      af[i] = *(const bf16x8*)(&As[cur][(wm + i * 16 + l15) * 32 + swz_ro]);
#pragma unroll
    for (int j = 0; j < 4; ++j)
      bfr[j] = *(const bf16x8*)(&Bs[cur][(wn + j * 16 + l15) * 32 + swz_ro]);
#pragma unroll
    for (int i = 0; i < 4; ++i)
#pragma unroll
      for (int j = 0; j < 4; ++j)
        acc[i][j] = __builtin_amdgcn_mfma_f32_16x16x32_bf16(af[i], bfr[j], acc[i][j], 0, 0, 0);
    __syncthreads();
    cur ^= 1;
  }

#pragma unroll
  for (int i = 0; i < 4; ++i)
#pragma unroll
    for (int r = 0; r < 4; ++r) {
      const int row = m0 + wm + i * 16 + l4 * 4 + r;
      const float ri = rsqrtf(ssum[row] * (1.0f / 2048.0f) + 1e-5f);
#pragma unroll
      for (int j = 0; j < 4; ++j) {
        const int col = n0 + wn + j * 16 + l15;
        const size_t idx = (size_t)row * 2048 + col;
        const float v = ri * acc[i][j][r];
        if (f32out) ((float*)out)[idx] = v;
        else        ((bf16*)out)[idx]  = (bf16)v;
      }
    }
}

// ---------------------------------------------------------------------------
extern "C" void kernel_launch(void* const* d_in, const int* in_sizes, int n_in,
                              void* d_out, int out_size, void* d_ws, size_t ws_size,
                              hipStream_t stream) {
  const void* hs     = d_in[0];                // [2,1024,2048]  fp32 (or bf16)
  const int*  pos    = (const int*)d_in[1];    // [2,1024] int32
  const void* w_qkv  = d_in[2];                // [3072,2048]
  const void* w_o    = d_in[3];                // [2048,2048]
  const void* norm_w = d_in[4];                // [2048]

  char* ws = (char*)d_ws;
  bf16*  hs_b   = (bf16*) (ws);                   //  8,388,608
  bf16*  wqkv_b = (bf16*) (ws + 8388608);         // 12,582,912
  bf16*  w_o_b  = (bf16*) (ws + 20971520);        //  8,388,608 (norm_w folded)
  float* ssum   = (float*)(ws + 29360128);        //      8,192
  bf16*  Qr     = (bf16*) (ws + 29368320);        //  8,388,608
  bf16*  Kr     = (bf16*) (ws + 37756928);        //  2,097,152
  bf16*  Vtr    = (bf16*) (ws + 39854080);        //  2,097,152
  bf16*  attn_o = (bf16*) (ws + 41951232);        //  8,388,608 (ends ~50.3 MB)

  convert_all<<<14336, 256, 0, stream>>>(hs, w_qkv, w_o, norm_w,
                                         hs_b, wqkv_b, w_o_b, ssum);
  gemm_qkv_rope<<<dim3(24, 16), 256, 0, stream>>>(hs_b, wqkv_b, pos, Qr, Kr, Vtr);
  attn_kernel<<<dim3(8, 64), 256, 0, stream>>>(Qr, Kr, Vtr, attn_o, ssum);
  gemm_out<<<dim3(16, 16), 256, 0, stream>>>(attn_o, w_o_b, ssum,
                                             (const unsigned int*)hs, d_out);
}

// Round 3
// 205.033 us; speedup vs baseline: 1.2620x; 1.2620x over previous
//
#include <hip/hip_runtime.h>
#include <hip/hip_bf16.h>
#include <cstdint>
#include <cstddef>

typedef __bf16 bf16;
typedef __bf16 bf16x2 __attribute__((ext_vector_type(2)));
typedef __bf16 bf16x4 __attribute__((ext_vector_type(4)));
typedef __bf16 bf16x8 __attribute__((ext_vector_type(8)));
typedef float  f32x4  __attribute__((ext_vector_type(4)));

// async global->LDS, 16B per lane. LDS dest = wave-uniform base + lane*16B.
__device__ __forceinline__ void async_copy16(const void* g, void* l) {
  __builtin_amdgcn_global_load_lds((const __attribute__((address_space(1))) void*)g,
                                   (__attribute__((address_space(3))) void*)l,
                                   16, 0, 0);
}

// LDS 64B-row swizzle: elem ^= ((row>>1)&3)<<3. Involution confined to the
// 32-elem row; spreads the 16-lane ds_read_b128 window (rows at 64B stride,
// fixed col) across all eight 16B bank-groups: 8-way conflict -> 2-way (free).
// Applied as inverse on the global SOURCE of global_load_lds (LDS dest stays
// linear, rule #21) and on the ds_read col. Addressing-only: no structure,
// occupancy, or instruction-count change vs the round-0 baseline.
__device__ __forceinline__ int swz(int row) { return ((row >> 1) & 3) << 3; }

// Per-block dtype flag from hs[0..127] words: fp32 mantissa-garbage decoded as
// bf16 has exponent >= 134 ~50% of the time; real bf16 N(0,1) never does.
__device__ __forceinline__ bool block_flag_is_f32(const unsigned int* w, int tid,
                                                  int* sflag) {
  if (tid < 64) {
    int weird = 0;
#pragma unroll
    for (int c = 0; c < 2; ++c) {
      const unsigned int lo = w[c * 64 + tid] & 0xffffu;
      const unsigned int ex = (lo >> 7) & 0xffu;
      if (ex >= 134u) ++weird;
    }
    const unsigned long long m1 = __ballot(weird >= 1);
    const unsigned long long m2 = __ballot(weird == 2);
    if (tid == 0) *sflag = (__popcll(m1) + __popcll(m2) >= 8) ? 1 : 0;
  }
  __syncthreads();
  return *sflag != 0;
}

// ---------------------------------------------------------------------------
// Fused convert (float4-unit indexed), flag computed per-block, block 0 also
// zero-inits ssum[2048].
// ---------------------------------------------------------------------------
__global__ __launch_bounds__(256) void convert_all(
    const void* __restrict__ s0, const void* __restrict__ s1,
    const void* __restrict__ s2, const void* __restrict__ s3,
    bf16* __restrict__ d0, bf16* __restrict__ d1, bf16* __restrict__ d2,
    float* __restrict__ ssum) {
  __shared__ int sflag;
  const int tid = threadIdx.x;
  const bool f32 = block_flag_is_f32((const unsigned int*)s0, tid, &sflag);
  if (blockIdx.x == 0) {
    ((float4*)ssum)[tid * 2]     = make_float4(0.f, 0.f, 0.f, 0.f);
    ((float4*)ssum)[tid * 2 + 1] = make_float4(0.f, 0.f, 0.f, 0.f);
  }
  const int i = blockIdx.x * 256 + tid;
  if (i >= 3670016) return;
  const void* src; bf16* dst; int off; bool fold = false;
  if      (i < 1048576) { src = s0; dst = d0; off = i; }
  else if (i < 2621440) { src = s1; dst = d1; off = i - 1048576; }
  else                  { src = s2; dst = d2; off = i - 2621440; fold = true; }
  float v[4];
  if (f32) {
    const float4 t = ((const float4*)src)[off];
    v[0] = t.x; v[1] = t.y; v[2] = t.z; v[3] = t.w;
  } else {
    const bf16x4 t = ((const bf16x4*)src)[off];
#pragma unroll
    for (int j = 0; j < 4; ++j) v[j] = (float)t[j];
  }
  if (fold) {
    const int k0 = (off * 4) & 2047;
#pragma unroll
    for (int j = 0; j < 4; ++j) {
      const float w = f32 ? ((const float*)s3)[k0 + j] : (float)((const bf16*)s3)[k0 + j];
      v[j] *= w;
    }
  }
  bf16x4 o;
#pragma unroll
  for (int j = 0; j < 4; ++j) o[j] = (bf16)v[j];
  *(bf16x4*)(dst + (size_t)off * 4) = o;
}

// ---------------------------------------------------------------------------
// GEMM1 + fused neox RoPE epilogue. Round-0 structure (tile 64x128, BK=128,
// grid 24x32 = 768 blocks -> ~3 blocks/CU) + swizzled staging/reads.
// V is written with seq permuted within 32-blocks: s' = (s&~31) + κ⁻¹(s&31),
// κ⁻¹(k) = (k&15)*2 + (k>>4), matching attention's packed-P key order.
// ---------------------------------------------------------------------------
__global__ __launch_bounds__(256) void gemm_qkv_rope(
    const bf16* __restrict__ A, const bf16* __restrict__ B,
    const int* __restrict__ pos,
    bf16* __restrict__ Q, bf16* __restrict__ K, bf16* __restrict__ V)
{
  __shared__ __align__(16) bf16 As[4 * 64 * 32];    // 16KB [kc][row][32]
  __shared__ __align__(16) bf16 Bs[4 * 128 * 32];   // 32KB [kc][row][32]
  const int tid = threadIdx.x, wave = tid >> 6, lane = tid & 63;
  const int l15 = lane & 15, l4 = lane >> 4;
  const int m0 = blockIdx.y * 64, n0 = blockIdx.x * 128;
  const int wm = (wave >> 1) * 32, wn = (wave & 1) * 64;
  const int KD = 2048;
  const int swz_ro = (l4 * 8) ^ swz(l15);   // fragment rows ≡ l15 (mod 16)

  f32x4 acc[2][4] = {};

  for (int kt = 0; kt < KD; kt += 128) {
#pragma unroll
    for (int c = 0; c < 4; ++c) {      // A: 4 chunks of 64x32
      const int e = c * 2048 + tid * 8;
      const int kc = e >> 11, row = (e >> 5) & 63;
      const int o = (e & 31) ^ swz(row);
      async_copy16(A + (size_t)(m0 + row) * KD + kt + kc * 32 + o, As + e);
    }
#pragma unroll
    for (int c = 0; c < 8; ++c) {      // B: 8 chunks -> 4 kc of 128x32
      const int e = c * 2048 + tid * 8;
      const int kc = e >> 12, row = (e >> 5) & 127;
      const int o = (e & 31) ^ swz(row);
      async_copy16(B + (size_t)(n0 + row) * KD + kt + kc * 32 + o, Bs + e);
    }
    __syncthreads();
#pragma unroll
    for (int s = 0; s < 4; ++s) {
      bf16x8 af[2], bfr[4];
#pragma unroll
      for (int i = 0; i < 2; ++i)
        af[i] = *(const bf16x8*)(As + s * 2048 + (wm + i * 16 + l15) * 32 + swz_ro);
#pragma unroll
      for (int j = 0; j < 4; ++j)
        bfr[j] = *(const bf16x8*)(Bs + s * 4096 + (wn + j * 16 + l15) * 32 + swz_ro);
#pragma unroll
      for (int i = 0; i < 2; ++i)
#pragma unroll
        for (int j = 0; j < 4; ++j)
          acc[i][j] = __builtin_amdgcn_mfma_f32_16x16x32_bf16(af[i], bfr[j], acc[i][j], 0, 0, 0);
    }
    __syncthreads();
  }

  if (n0 < 2560) {  // Q or K: rope in-register
    const bool isQ = (n0 < 2048);
#pragma unroll
    for (int i = 0; i < 2; ++i)
#pragma unroll
      for (int j = 0; j < 4; ++j) {
        const int col = n0 + wn + j * 16 + l15;
        const int hd = isQ ? col : (col - 2048);
        const int hh = hd >> 6, d = hd & 63;
        const int fi = d & 31;
        const float ifr = __expf((float)fi * -0.41007385554f);  // theta^(-fi/32)
#pragma unroll
        for (int r = 0; r < 4; ++r) {
          const int m = m0 + wm + i * 16 + l4 * 4 + r;
          const int b = m >> 10, s = m & 1023;
          const float ang = (float)pos[m] * ifr;
          float sn, cs;
          __sincosf(ang, &sn, &cs);
          const float x  = acc[i][j][r];
          const float xp = acc[i][j ^ 2][r];   // partner (col^32)
          const float v = (d < 32) ? (x * cs - xp * sn) : (x * cs + xp * sn);
          if (isQ) Q[(((size_t)(b * 32 + hh)) * 1024 + s) * 64 + d] = (bf16)(v * 0.125f);
          else     K[(((size_t)(b * 8 + hh)) * 1024 + s) * 64 + d] = (bf16)v;
        }
      }
  } else {          // V: transpose to [B,NKV,64,S], seq permuted within 32
#pragma unroll
    for (int i = 0; i < 2; ++i)
#pragma unroll
      for (int j = 0; j < 4; ++j) {
        const int cv = n0 + wn + j * 16 + l15 - 2560;
        const int hh = cv >> 6, d = cv & 63;
#pragma unroll
        for (int r = 0; r < 4; ++r) {
          const int m = m0 + wm + i * 16 + l4 * 4 + r;
          const int b = m >> 10, s = m & 1023;
          const int sp = (s & ~31) + ((s & 15) * 2 + ((s >> 4) & 1));
          V[(((size_t)(b * 8 + hh)) * 64 + d) * 1024 + sp] = (bf16)acc[i][j][r];
        }
      }
  }
}

// ---------------------------------------------------------------------------
// Flash attention — round-0 code verbatim (round-6 numerics, __expf softmax,
// 2 barriers/tile, global_load_lds staging) + swizzled staging/reads only.
// P path (stride-40 rows, same-wave write/read) left untouched.
// ---------------------------------------------------------------------------
__global__ __launch_bounds__(256) void attn_kernel(
    const bf16* __restrict__ Q, const bf16* __restrict__ K,
    const bf16* __restrict__ Vt, bf16* __restrict__ O, float* __restrict__ ssum)
{
  __shared__ __align__(16) bf16 Ks[2 * 128 * 32];   // 16KB [dchunk][key][32]
  __shared__ __align__(16) bf16 Vs[4 * 64 * 32];    // 16KB [kchunk][d][32]
  __shared__ __align__(16) bf16 Ps[4 * 128 * 40];   // 40KB [kchunk][q][40]; Q-stage reuse

  const int tid = threadIdx.x, wave = tid >> 6, lane = tid & 63;
  const int l15 = lane & 15, l4 = lane >> 4;
  const int swz_ro = (l4 * 8) ^ swz(l15);
  const int ip = blockIdx.x, bh = blockIdx.y;
  const int b = bh >> 5, h = bh & 31, kvh = h >> 2;
  const int qlo = ip * 64, qhi = (15 - ip) * 64;
  const bf16* Qb = Q + ((size_t)(b * 32 + h)) * 65536;
  const bf16* Kb = K + ((size_t)(b * 8 + kvh)) * 65536;
  const bf16* Vb = Vt + ((size_t)(b * 8 + kvh)) * 65536;

#pragma unroll
  for (int c = 0; c < 4; ++c) {
    const int e = c * 2048 + tid * 8;
    const int dchunk = e >> 12;
    const int row = (e & 4095) >> 5;
    const int qb = (row < 64) ? qlo : qhi;
    const int o = (e & 31) ^ swz(row);
    async_copy16(Qb + (size_t)(qb + (row & 63)) * 64 + dchunk * 32 + o, Ps + e);
  }
  __syncthreads();
  bf16x8 aq[2][2];   // [half][dchunk]
#pragma unroll
  for (int i = 0; i < 2; ++i)
#pragma unroll
    for (int s = 0; s < 2; ++s)
      aq[i][s] = *(const bf16x8*)(Ps + s * 4096 + (i * 64 + wave * 16 + l15) * 32 + swz_ro);
  __syncthreads();

  float m_s[2][4], l_s[2][4];
  f32x4 o_acc[2][4] = {};
#pragma unroll
  for (int i = 0; i < 2; ++i)
#pragma unroll
    for (int r = 0; r < 4; ++r) { m_s[i][r] = -3.0e4f; l_s[i][r] = 0.f; }

  const int nkt = (1151 - 64 * ip) >> 7;
  for (int kt = 0; kt < nkt; ++kt) {
    const int k0 = kt * 128;
    const bool lo_act = (k0 < (ip + 1) * 64);
#pragma unroll
    for (int c = 0; c < 4; ++c) {
      const int e = c * 2048 + tid * 8;
      const int krow = (e & 4095) >> 5;
      const int ko = (e & 31) ^ swz(krow);
      async_copy16(Kb + (size_t)(k0 + krow) * 64 + (e >> 12) * 32 + ko, Ks + e);
      const int drow = (e & 2047) >> 5;
      const int vo = (e & 31) ^ swz(drow);
      async_copy16(Vb + (size_t)drow * 1024 + k0 + (e >> 11) * 32 + vo, Vs + e);
    }
    __syncthreads();

    f32x4 sc[2][8] = {};
#pragma unroll
    for (int j = 0; j < 8; ++j) {
      const bf16x8 bk0 = *(const bf16x8*)(Ks + (j * 16 + l15) * 32 + swz_ro);
      const bf16x8 bk1 = *(const bf16x8*)(Ks + 4096 + (j * 16 + l15) * 32 + swz_ro);
      sc[1][j] = __builtin_amdgcn_mfma_f32_16x16x32_bf16(aq[1][0], bk0, sc[1][j], 0, 0, 0);
      sc[1][j] = __builtin_amdgcn_mfma_f32_16x16x32_bf16(aq[1][1], bk1, sc[1][j], 0, 0, 0);
      if (lo_act) {
        sc[0][j] = __builtin_amdgcn_mfma_f32_16x16x32_bf16(aq[0][0], bk0, sc[0][j], 0, 0, 0);
        sc[0][j] = __builtin_amdgcn_mfma_f32_16x16x32_bf16(aq[0][1], bk1, sc[0][j], 0, 0, 0);
      }
    }

#pragma unroll
    for (int hh = 0; hh < 2; ++hh) {
      if (hh == 0 && !lo_act) continue;
      const int qb = hh ? qhi : qlo;
#pragma unroll
      for (int r = 0; r < 4; ++r) {
        const int rl = wave * 16 + l4 * 4 + r;
        const int rg = qb + rl;
        float mx = -3.0e4f;
#pragma unroll
        for (int j = 0; j < 8; ++j) {
          float v = sc[hh][j][r];
          if (k0 + j * 16 + l15 > rg) v = -3.0e4f;
          sc[hh][j][r] = v;
          mx = fmaxf(mx, v);
        }
#pragma unroll
        for (int off = 1; off < 16; off <<= 1) mx = fmaxf(mx, __shfl_xor(mx, off));
        const float mnew = fmaxf(m_s[hh][r], mx);
        const float alpha = __expf(m_s[hh][r] - mnew);
        m_s[hh][r] = mnew;
        float rs = 0.f;
#pragma unroll
        for (int t = 0; t < 4; ++t) {
          const float pv0 = __expf(sc[hh][2 * t][r]     - mnew);
          const float pv1 = __expf(sc[hh][2 * t + 1][r] - mnew);
          rs += pv0 + pv1;
          bf16x2 pk; pk[0] = (bf16)pv0; pk[1] = (bf16)pv1;
          *(bf16x2*)(Ps + t * 5120 + (hh * 64 + rl) * 40 + l15 * 2) = pk;
        }
#pragma unroll
        for (int off = 1; off < 16; off <<= 1) rs += __shfl_xor(rs, off);
        l_s[hh][r] = l_s[hh][r] * alpha + rs;
#pragma unroll
        for (int jd = 0; jd < 4; ++jd) o_acc[hh][jd][r] *= alpha;
      }
    }
    // NOTE: no __syncthreads here — P rows are written and read by the same
    // wave (A-frag row = hh*64 + wave*16 + l15); LDS ops are wave-ordered.

#pragma unroll
    for (int ks = 0; ks < 4; ++ks) {
      bf16x8 bv[4];
#pragma unroll
      for (int jd = 0; jd < 4; ++jd)
        bv[jd] = *(const bf16x8*)(Vs + ks * 2048 + (jd * 16 + l15) * 32 + swz_ro);
#pragma unroll
      for (int hh = 0; hh < 2; ++hh) {
        if (hh == 0 && !lo_act) continue;
        const bf16x8 ap = *(const bf16x8*)(Ps + ks * 5120 + (hh * 64 + wave * 16 + l15) * 40 + l4 * 8);
#pragma unroll
        for (int jd = 0; jd < 4; ++jd)
          o_acc[hh][jd] = __builtin_amdgcn_mfma_f32_16x16x32_bf16(ap, bv[jd], o_acc[hh][jd], 0, 0, 0);
      }
    }
    __syncthreads();
  }

  // ---- epilogue: O /= l, write [B*S, NH*64]; accumulate row sum-of-squares
#pragma unroll
  for (int hh = 0; hh < 2; ++hh) {
    const int qb = hh ? qhi : qlo;
#pragma unroll
    for (int r = 0; r < 4; ++r) {
      const float inv = 1.0f / l_s[hh][r];
      const int srow = qb + wave * 16 + l4 * 4 + r;
      bf16* op = O + ((size_t)(b * 1024 + srow)) * 2048 + h * 64;
      float ss = 0.f;
#pragma unroll
      for (int jd = 0; jd < 4; ++jd) {
        const float v = o_acc[hh][jd][r] * inv;
        op[jd * 16 + l15] = (bf16)v;
        ss += v * v;
      }
#pragma unroll
      for (int off = 1; off < 16; off <<= 1) ss += __shfl_xor(ss, off);
      if (l15 == 0) atomicAdd(&ssum[b * 1024 + srow], ss);
    }
  }
}

// ---------------------------------------------------------------------------
// GEMM2: out = rsqrt(mean(ssum)+eps)[m] * (attn_o x w_o'^T). Round-0
// structure (BK=128, grid 16x32) + swizzled staging/reads.
// ---------------------------------------------------------------------------
__global__ __launch_bounds__(256) void gemm_out(
    const bf16* __restrict__ A, const bf16* __restrict__ B,
    const float* __restrict__ ssum, const unsigned int* __restrict__ hs_raw,
    void* __restrict__ out)
{
  __shared__ __align__(16) bf16 As[4 * 64 * 32];    // 16KB
  __shared__ __align__(16) bf16 Bs[4 * 128 * 32];   // 32KB
  __shared__ int sflag;
  const int tid = threadIdx.x, wave = tid >> 6, lane = tid & 63;
  const bool f32out = block_flag_is_f32(hs_raw, tid, &sflag);
  const int l15 = lane & 15, l4 = lane >> 4;
  const int m0 = blockIdx.y * 64, n0 = blockIdx.x * 128;
  const int wm = (wave >> 1) * 32, wn = (wave & 1) * 64;
  const int KD = 2048;
  const int swz_ro = (l4 * 8) ^ swz(l15);

  f32x4 acc[2][4] = {};

  for (int kt = 0; kt < KD; kt += 128) {
#pragma unroll
    for (int c = 0; c < 4; ++c) {
      const int e = c * 2048 + tid * 8;
      const int kc = e >> 11, row = (e >> 5) & 63;
      const int o = (e & 31) ^ swz(row);
      async_copy16(A + (size_t)(m0 + row) * KD + kt + kc * 32 + o, As + e);
    }
#pragma unroll
    for (int c = 0; c < 8; ++c) {
      const int e = c * 2048 + tid * 8;
      const int kc = e >> 12, row = (e >> 5) & 127;
      const int o = (e & 31) ^ swz(row);
      async_copy16(B + (size_t)(n0 + row) * KD + kt + kc * 32 + o, Bs + e);
    }
    __syncthreads();
#pragma unroll
    for (int s = 0; s < 4; ++s) {
      bf16x8 af[2], bfr[4];
#pragma unroll
      for (int i = 0; i < 2; ++i)
        af[i] = *(const bf16x8*)(As + s * 2048 + (wm + i * 16 + l15) * 32 + swz_ro);
#pragma unroll
      for (int j = 0; j < 4; ++j)
        bfr[j] = *(const bf16x8*)(Bs + s * 4096 + (wn + j * 16 + l15) * 32 + swz_ro);
#pragma unroll
      for (int i = 0; i < 2; ++i)
#pragma unroll
        for (int j = 0; j < 4; ++j)
          acc[i][j] = __builtin_amdgcn_mfma_f32_16x16x32_bf16(af[i], bfr[j], acc[i][j], 0, 0, 0);
    }
    __syncthreads();
  }

#pragma unroll
  for (int i = 0; i < 2; ++i)
#pragma unroll
    for (int r = 0; r < 4; ++r) {
      const int row = m0 + wm + i * 16 + l4 * 4 + r;
      const float ri = rsqrtf(ssum[row] * (1.0f / 2048.0f) + 1e-5f);
#pragma unroll
      for (int j = 0; j < 4; ++j) {
        const int col = n0 + wn + j * 16 + l15;
        const size_t idx = (size_t)row * 2048 + col;
        const float v = ri * acc[i][j][r];
        if (f32out) ((float*)out)[idx] = v;
        else        ((bf16*)out)[idx]  = (bf16)v;
      }
    }
}

// ---------------------------------------------------------------------------
extern "C" void kernel_launch(void* const* d_in, const int* in_sizes, int n_in,
                              void* d_out, int out_size, void* d_ws, size_t ws_size,
                              hipStream_t stream) {
  const void* hs     = d_in[0];                // [2,1024,2048]  fp32 (or bf16)
  const int*  pos    = (const int*)d_in[1];    // [2,1024] int32
  const void* w_qkv  = d_in[2];                // [3072,2048]
  const void* w_o    = d_in[3];                // [2048,2048]
  const void* norm_w = d_in[4];                // [2048]

  char* ws = (char*)d_ws;
  bf16*  hs_b   = (bf16*) (ws);                   //  8,388,608
  bf16*  wqkv_b = (bf16*) (ws + 8388608);         // 12,582,912
  bf16*  w_o_b  = (bf16*) (ws + 20971520);        //  8,388,608 (norm_w folded)
  float* ssum   = (float*)(ws + 29360128);        //      8,192
  bf16*  Qr     = (bf16*) (ws + 29368320);        //  8,388,608
  bf16*  Kr     = (bf16*) (ws + 37756928);        //  2,097,152
  bf16*  Vtr    = (bf16*) (ws + 39854080);        //  2,097,152
  bf16*  attn_o = (bf16*) (ws + 41951232);        //  8,388,608 (ends ~50.3 MB)

  convert_all<<<14336, 256, 0, stream>>>(hs, w_qkv, w_o, norm_w,
                                         hs_b, wqkv_b, w_o_b, ssum);
  gemm_qkv_rope<<<dim3(24, 32), 256, 0, stream>>>(hs_b, wqkv_b, pos, Qr, Kr, Vtr);
  attn_kernel<<<dim3(8, 64), 256, 0, stream>>>(Qr, Kr, Vtr, attn_o, ssum);
  gemm_out<<<dim3(16, 32), 256, 0, stream>>>(attn_o, w_o_b, ssum,
                                             (const unsigned int*)hs, d_out);
}